// Round 13
// baseline (310.464 us; speedup 1.0000x reference)
//
#include <hip/hip_runtime.h>
#include <cstdint>

#define TPB 256

typedef __attribute__((ext_vector_type(8))) short short8_t;   // 8 bf16
typedef __attribute__((ext_vector_type(4))) float f32x4;
typedef __attribute__((ext_vector_type(2))) float f32x2;

__device__ __forceinline__ float lrelu(float x) { return x > 0.0f ? x : 0.2f * x; }

// round-to-nearest-even fp32 -> bf16
__device__ __forceinline__ unsigned short f2bf(float x) {
    unsigned int u = __float_as_uint(x);
    unsigned int r = (u + 0x7FFFu + ((u >> 16) & 1u)) >> 16;
    return (unsigned short)r;
}
__device__ __forceinline__ float bf_lo(unsigned int u) { return __uint_as_float(u << 16); }
__device__ __forceinline__ float bf_hi(unsigned int u) { return __uint_as_float(u & 0xFFFF0000u); }

// ---------------- graph build ----------------
__global__ void k_setflag(const int* __restrict__ midx, int* __restrict__ flag, int m) {
    int i = blockIdx.x * TPB + threadIdx.x;
    if (i < m) flag[midx[i]] = 1;
}

// cnt padded: one counter per 128B line (stride 32 ints)
__global__ void k_count_rank(const int* __restrict__ dst, int* __restrict__ cnt,
                             int* __restrict__ rank, int e) {
    int i = blockIdx.x * TPB + threadIdx.x;
    if (i < e) rank[i] = atomicAdd(&cnt[dst[i] << 5], 1);
}

// exclusive scan over padded cnt (stride 32), dense rp out; 2048 elems/block
__global__ void k_scan_block(const int* __restrict__ cnt, int* __restrict__ rp,
                             int* __restrict__ bsum, int n) {
    __shared__ int ls[TPB];
    int t = threadIdx.x, b = blockIdx.x;
    int base = b * 2048 + t * 8;
    int c[8];
    int tsum = 0;
#pragma unroll
    for (int j = 0; j < 8; ++j) {
        int idx = base + j;
        c[j] = (idx < n) ? cnt[idx << 5] : 0;
        tsum += c[j];
    }
    ls[t] = tsum;
    __syncthreads();
    for (int off = 1; off < TPB; off <<= 1) {
        int v = (t >= off) ? ls[t - off] : 0;
        __syncthreads();
        ls[t] += v;
        __syncthreads();
    }
    int run = ls[t] - tsum;
#pragma unroll
    for (int j = 0; j < 8; ++j) {
        int idx = base + j;
        if (idx < n) rp[idx] = run;
        run += c[j];
    }
    if (t == TPB - 1) bsum[b] = ls[TPB - 1];
}

__global__ void k_scan_sums(int* __restrict__ bsum, int* __restrict__ rp, int nb, int n) {
    int l = threadIdx.x;
    int v = (l < nb) ? bsum[l] : 0;
    int inc = v;
    for (int off = 1; off < 64; off <<= 1) {
        int u = __shfl_up(inc, off);
        if (l >= off) inc += u;
    }
    int tot = __shfl(inc, 63);
    if (l < nb) bsum[l] = inc - v;
    if (l == 0) rp[n] = tot;
}

__global__ void k_scan_add(int* __restrict__ rp, const int* __restrict__ bsum, int n) {
    int b = blockIdx.x;
    int base_v = bsum[b];
    for (int i = threadIdx.x; i < 2048; i += TPB) {
        int idx = b * 2048 + i;
        if (idx < n) rp[idx] += base_v;
    }
}

__global__ void k_fill(const int* __restrict__ dst, const int* __restrict__ src,
                       const int* __restrict__ rank, const int* __restrict__ rp,
                       int* __restrict__ csrc, int e) {
    int i = blockIdx.x * TPB + threadIdx.x;
    if (i < e) csrc[rp[dst[i]] + rank[i]] = src[i];
}

// ---------------- W -> B-fragment pack (bf16) ----------------
__global__ void k_packW(const float* __restrict__ W, unsigned short* __restrict__ Bp) {
    int t = blockIdx.x * TPB + threadIdx.x;
    if (t >= 2048) return;
    int kb = t >> 7, n = t & 127;
    unsigned int w[4];
#pragma unroll
    for (int j = 0; j < 4; ++j) {
        unsigned int lo = f2bf(W[(kb * 8 + 2 * j) * 128 + n]);
        unsigned int hi = f2bf(W[(kb * 8 + 2 * j + 1) * 128 + n]);
        w[j] = lo | (hi << 16);
    }
    reinterpret_cast<uint4*>(Bp)[t] = make_uint4(w[0], w[1], w[2], w[3]);
}

// ---------------- MFMA bf16 GEMM + fused el/er; LDS-free ----------------
template <int MASKED, int BF16IN, int FP8OUT>
__global__ __launch_bounds__(TPB) void k_gemm_mfma(
    const void* __restrict__ Ain, const int* __restrict__ flag,
    const float* __restrict__ mtok, const unsigned short* __restrict__ Bpack,
    const float* __restrict__ al, const float* __restrict__ ar,
    void* __restrict__ Fout, float* __restrict__ EL, float* __restrict__ ER, int n)
{
    int t = threadIdx.x;
    int bm0 = blockIdx.x * 128;
    int w = t >> 6, l = t & 63;
    int lm = l & 15, lg = l >> 4;
    const short8_t* bp = reinterpret_cast<const short8_t*>(Bpack);   // global, L2-hit

    int rowA0 = bm0 + w * 32 + lm;
    int rowA1 = rowA0 + 16;
    int rc0 = rowA0 < n ? rowA0 : n - 1;
    int rc1 = rowA1 < n ? rowA1 : n - 1;

    short8_t af0[4], af1[4];
    if (BF16IN) {
        const unsigned short* A = (const unsigned short*)Ain;
        const unsigned short* pA0 = A + (size_t)rc0 * 128 + lg * 8;
        const unsigned short* pA1 = A + (size_t)rc1 * 128 + lg * 8;
#pragma unroll
        for (int ks = 0; ks < 4; ++ks) {
            af0[ks] = *reinterpret_cast<const short8_t*>(pA0 + ks * 32);
            af1[ks] = *reinterpret_cast<const short8_t*>(pA1 + ks * 32);
        }
    } else {
        const float* A = (const float*)Ain;
        const float* pA0 = A + (size_t)rc0 * 128 + lg * 8;
        const float* pA1 = A + (size_t)rc1 * 128 + lg * 8;
        if (MASKED) {
            if (flag[rc0]) pA0 = mtok + lg * 8;
            if (flag[rc1]) pA1 = mtok + lg * 8;
        }
#pragma unroll
        for (int ks = 0; ks < 4; ++ks) {
            float4 lo0 = *reinterpret_cast<const float4*>(pA0 + ks * 32);
            float4 hi0 = *reinterpret_cast<const float4*>(pA0 + ks * 32 + 4);
            float4 lo1 = *reinterpret_cast<const float4*>(pA1 + ks * 32);
            float4 hi1 = *reinterpret_cast<const float4*>(pA1 + ks * 32 + 4);
            short8_t v0, v1;
            v0[0] = (short)f2bf(lo0.x); v0[1] = (short)f2bf(lo0.y);
            v0[2] = (short)f2bf(lo0.z); v0[3] = (short)f2bf(lo0.w);
            v0[4] = (short)f2bf(hi0.x); v0[5] = (short)f2bf(hi0.y);
            v0[6] = (short)f2bf(hi0.z); v0[7] = (short)f2bf(hi0.w);
            v1[0] = (short)f2bf(lo1.x); v1[1] = (short)f2bf(lo1.y);
            v1[2] = (short)f2bf(lo1.z); v1[3] = (short)f2bf(lo1.w);
            v1[4] = (short)f2bf(hi1.x); v1[5] = (short)f2bf(hi1.y);
            v1[6] = (short)f2bf(hi1.z); v1[7] = (short)f2bf(hi1.w);
            af0[ks] = v0; af1[ks] = v1;
        }
    }

    f32x4 acc[2][8];
#pragma unroll
    for (int mf = 0; mf < 2; ++mf)
#pragma unroll
        for (int f = 0; f < 8; ++f)
            acc[mf][f] = (f32x4){0.f, 0.f, 0.f, 0.f};

#pragma unroll
    for (int ks = 0; ks < 4; ++ks) {
        int kb = ks * 4 + lg;
#pragma unroll
        for (int f = 0; f < 8; ++f) {
            short8_t bfr = bp[kb * 128 + f * 16 + lm];
            acc[0][f] = __builtin_amdgcn_mfma_f32_16x16x32_bf16(af0[ks], bfr, acc[0][f], 0, 0, 0);
            acc[1][f] = __builtin_amdgcn_mfma_f32_16x16x32_bf16(af1[ks], bfr, acc[1][f], 0, 0, 0);
        }
    }

    float alv[8], arv[8];
#pragma unroll
    for (int f = 0; f < 8; ++f) { alv[f] = al[f * 16 + lm]; arv[f] = ar[f * 16 + lm]; }

#pragma unroll
    for (int mf = 0; mf < 2; ++mf) {
#pragma unroll
        for (int r = 0; r < 4; ++r) {
            int row = bm0 + w * 32 + mf * 16 + lg * 4 + r;
            if (row < n) {
                if (FP8OUT) {
                    unsigned char* Ff = (unsigned char*)Fout;
#pragma unroll
                    for (int f = 0; f < 8; ++f) {
                        int pk = __builtin_amdgcn_cvt_pk_fp8_f32(acc[mf][f][r], acc[mf][f][r], 0, false);
                        Ff[(size_t)row * 128 + f * 16 + lm] = (unsigned char)(pk & 0xFF);
                    }
                } else {
                    unsigned short* Fb = (unsigned short*)Fout;
#pragma unroll
                    for (int f = 0; f < 8; ++f)
                        Fb[(size_t)row * 128 + f * 16 + lm] = f2bf(acc[mf][f][r]);
                }
            }
            float pe[4], pr_[4];
#pragma unroll
            for (int h = 0; h < 4; ++h) {
                pe[h]  = acc[mf][2 * h][r] * alv[2 * h] + acc[mf][2 * h + 1][r] * alv[2 * h + 1];
                pr_[h] = acc[mf][2 * h][r] * arv[2 * h] + acc[mf][2 * h + 1][r] * arv[2 * h + 1];
            }
#pragma unroll
            for (int h = 0; h < 4; ++h) {
#pragma unroll
                for (int off = 1; off < 16; off <<= 1) {
                    pe[h]  += __shfl_xor(pe[h], off);
                    pr_[h] += __shfl_xor(pr_[h], off);
                }
            }
            if (lm == 0 && row < n) {
                *reinterpret_cast<float4*>(EL + (size_t)row * 4) = make_float4(pe[0], pe[1], pe[2], pe[3]);
                *reinterpret_cast<float4*>(ER + (size_t)row * 4) = make_float4(pr_[0], pr_[1], pr_[2], pr_[3]);
            }
        }
    }
}

// ---------------- layer-0 agg: fp8 gather, 4 edge-slots, 2-deep pipeline ----------------
// wave per node; lane: edge-slot j = l>>4 (4 edges/iter), octet q = l&15 (8B, 8 feats).
// csrc prefetched 2 iters ahead; EL/F issued for an already-returned index ->
// no intra-iteration dependent-load chain.
__global__ __launch_bounds__(TPB) void k_node_agg8(
    const unsigned char* __restrict__ Ff,
    const float* __restrict__ EL, const float* __restrict__ ER,
    const float* __restrict__ bias,
    const int* __restrict__ rp, const int* __restrict__ csrc,
    unsigned short* __restrict__ OUT, int n)
{
    int l = threadIdx.x & 63;
    int v = blockIdx.x * 4 + (threadIdx.x >> 6);
    if (v >= n) return;
    int p0 = rp[v];
    int deg = rp[v + 1] - p0;
    int j = l >> 4, q = l & 15, h = q >> 2;

    if (deg == 0) {
        if (j == 0) {
            const float* bp = bias + q * 8;
            unsigned int od[4];
#pragma unroll
            for (int k = 0; k < 4; ++k) {
                float o0 = fmaxf(bp[2 * k], 0.f);
                float o1 = fmaxf(bp[2 * k + 1], 0.f);
                od[k] = (unsigned int)f2bf(o0) | ((unsigned int)f2bf(o1) << 16);
            }
            *reinterpret_cast<uint4*>(OUT + (size_t)v * 128 + q * 8) = make_uint4(od[0], od[1], od[2], od[3]);
        }
        return;
    }

    float er_h = ER[(size_t)v * 4 + h];
    f32x2 a[4];
#pragma unroll
    for (int k = 0; k < 4; ++k) a[k] = (f32x2){0.f, 0.f};
    float ssum = 0.f;
    int dm1 = deg - 1;
    int nit = (deg + 3) >> 2;

    // prologue: edge indices for it=0 and it=1 both in flight
    int i0 = (j <= dm1) ? j : dm1;
    int e1 = 4 + j; int i1 = (e1 <= dm1) ? e1 : dm1;
    int s0 = csrc[p0 + i0];
    int s1 = csrc[p0 + i1];
    float el0 = EL[(size_t)s0 * 4 + h];
    uint2 u0 = *reinterpret_cast<const uint2*>(Ff + (size_t)s0 * 128 + q * 8);

    for (int it = 0; it < nit; ++it) {
        int e2 = (it + 2) * 4 + j;
        int i2 = (e2 <= dm1) ? e2 : dm1;
        int s2 = csrc[p0 + i2];                        // 2 iters ahead (independent)
        float el1 = EL[(size_t)s1 * 4 + h];            // s1 returned last iter
        uint2 u1 = *reinterpret_cast<const uint2*>(Ff + (size_t)s1 * 128 + q * 8);
        float x = __expf(lrelu(el0 + er_h));
        x = (it * 4 + j <= dm1) ? x : 0.f;
        ssum += x;
        f32x2 x2 = {x, x};
        f32x2 c0 = __builtin_amdgcn_cvt_pk_f32_fp8(u0.x, false);
        f32x2 c1 = __builtin_amdgcn_cvt_pk_f32_fp8(u0.x, true);
        f32x2 c2 = __builtin_amdgcn_cvt_pk_f32_fp8(u0.y, false);
        f32x2 c3 = __builtin_amdgcn_cvt_pk_f32_fp8(u0.y, true);
        a[0] += x2 * c0;
        a[1] += x2 * c1;
        a[2] += x2 * c2;
        a[3] += x2 * c3;
        el0 = el1; u0 = u1; s1 = s2;
    }

#pragma unroll
    for (int off = 16; off <= 32; off <<= 1) {
#pragma unroll
        for (int k = 0; k < 4; ++k) {
            a[k].x += __shfl_xor(a[k].x, off);
            a[k].y += __shfl_xor(a[k].y, off);
        }
        ssum += __shfl_xor(ssum, off);
    }
    if (j == 0) {
        float inv = 1.0f / ssum;
        const float* bp = bias + q * 8;
        unsigned int od[4];
#pragma unroll
        for (int k = 0; k < 4; ++k) {
            float o0 = fmaxf(a[k].x * inv + bp[2 * k], 0.f);
            float o1 = fmaxf(a[k].y * inv + bp[2 * k + 1], 0.f);
            od[k] = (unsigned int)f2bf(o0) | ((unsigned int)f2bf(o1) << 16);
        }
        *reinterpret_cast<uint4*>(OUT + (size_t)v * 128 + q * 8) = make_uint4(od[0], od[1], od[2], od[3]);
    }
}

// ---------------- layer-1 agg: bf16 gather, mask-list nodes, 2-deep pipeline ----------------
template <int USE_LIST>
__global__ __launch_bounds__(TPB) void k_node_agg(
    const unsigned short* __restrict__ Fb,
    const float* __restrict__ EL, const float* __restrict__ ER,
    const float* __restrict__ bias,
    const int* __restrict__ rp, const int* __restrict__ csrc,
    const int* __restrict__ vlist,
    unsigned short* __restrict__ OUT, int nwork)
{
    int l = threadIdx.x & 63;
    int widx = blockIdx.x * 4 + (threadIdx.x >> 6);
    if (widx >= nwork) return;
    int v = USE_LIST ? vlist[widx] : widx;
    int p0 = rp[v];
    int deg = rp[v + 1] - p0;
    int j = l >> 4, q = l & 15, h = q >> 2;

    if (deg == 0) {
        if (j == 0) {
            const float* bp = bias + q * 8;
            unsigned int od[4];
#pragma unroll
            for (int k = 0; k < 4; ++k) {
                float o0 = fmaxf(bp[2 * k], 0.f);
                float o1 = fmaxf(bp[2 * k + 1], 0.f);
                od[k] = (unsigned int)f2bf(o0) | ((unsigned int)f2bf(o1) << 16);
            }
            *reinterpret_cast<uint4*>(OUT + (size_t)v * 128 + q * 8) = make_uint4(od[0], od[1], od[2], od[3]);
        }
        return;
    }

    const char* Fc  = (const char*)Fb;
    const char* ELc = (const char*)EL;
    float er_h = ER[(size_t)v * 4 + h];
    unsigned hq_el = (unsigned)h * 4u;
    unsigned q16   = (unsigned)q * 16u;

    f32x2 a0 = {0.f, 0.f}, a1 = {0.f, 0.f}, a2 = {0.f, 0.f}, a3 = {0.f, 0.f};
    float ssum = 0.f;
    int dm1 = deg - 1;
    int nit = (deg + 3) >> 2;

    int i0 = (j <= dm1) ? j : dm1;
    int e1 = 4 + j; int i1 = (e1 <= dm1) ? e1 : dm1;
    int s0 = csrc[p0 + i0];
    int s1 = csrc[p0 + i1];
    float el0 = *(const float*)(ELc + (unsigned)s0 * 16u + hq_el);
    uint4 u0  = *(const uint4*)(Fc + (unsigned)s0 * 256u + q16);

    for (int it = 0; it < nit; ++it) {
        int e2 = (it + 2) * 4 + j;
        int i2 = (e2 <= dm1) ? e2 : dm1;
        int s2 = csrc[p0 + i2];                        // 2 iters ahead
        float el1 = *(const float*)(ELc + (unsigned)s1 * 16u + hq_el);
        uint4 u1  = *(const uint4*)(Fc + (unsigned)s1 * 256u + q16);
        float x = __expf(lrelu(el0 + er_h));
        x = (it * 4 + j <= dm1) ? x : 0.f;
        ssum += x;
        f32x2 w0; w0.x = bf_lo(u0.x); w0.y = bf_hi(u0.x);
        f32x2 w1; w1.x = bf_lo(u0.y); w1.y = bf_hi(u0.y);
        f32x2 w2; w2.x = bf_lo(u0.z); w2.y = bf_hi(u0.z);
        f32x2 w3; w3.x = bf_lo(u0.w); w3.y = bf_hi(u0.w);
        a0 += x * w0; a1 += x * w1; a2 += x * w2; a3 += x * w3;
        el0 = el1; u0 = u1; s1 = s2;
    }

#pragma unroll
    for (int off = 16; off <= 32; off <<= 1) {
        a0.x += __shfl_xor(a0.x, off); a0.y += __shfl_xor(a0.y, off);
        a1.x += __shfl_xor(a1.x, off); a1.y += __shfl_xor(a1.y, off);
        a2.x += __shfl_xor(a2.x, off); a2.y += __shfl_xor(a2.y, off);
        a3.x += __shfl_xor(a3.x, off); a3.y += __shfl_xor(a3.y, off);
        ssum += __shfl_xor(ssum, off);
    }
    if (j == 0) {
        float inv = 1.0f / ssum;
        const float* bp = bias + q * 8;
        float o[8];
        o[0] = a0.x * inv + bp[0]; o[1] = a0.y * inv + bp[1];
        o[2] = a1.x * inv + bp[2]; o[3] = a1.y * inv + bp[3];
        o[4] = a2.x * inv + bp[4]; o[5] = a2.y * inv + bp[5];
        o[6] = a3.x * inv + bp[6]; o[7] = a3.y * inv + bp[7];
        unsigned int od[4];
#pragma unroll
        for (int k = 0; k < 4; ++k) {
            float o0 = fmaxf(o[2 * k], 0.f);
            float o1 = fmaxf(o[2 * k + 1], 0.f);
            od[k] = (unsigned int)f2bf(o0) | ((unsigned int)f2bf(o1) << 16);
        }
        *reinterpret_cast<uint4*>(OUT + (size_t)v * 128 + q * 8) = make_uint4(od[0], od[1], od[2], od[3]);
    }
}

// ---------------- decoder GEMM on mask rows (bf16 H) + squared-diff partial ----------------
__global__ __launch_bounds__(TPB) void k_loss(
    const unsigned short* __restrict__ H, const int* __restrict__ midx,
    const float* __restrict__ Wd, const float* __restrict__ bd,
    const float* __restrict__ attr, int m, float* __restrict__ part)
{
    __shared__ float sA[32][128];
    __shared__ float sW[128][128];
    __shared__ int srow[32];
    __shared__ float red[TPB];
    int t = threadIdx.x;
    int bm0 = blockIdx.x * 32;
    if (t < 32) {
        int i = bm0 + t;
        srow[t] = (i < m) ? midx[i] : -1;
    }
    for (int i = t; i < 4096; i += TPB)
        reinterpret_cast<float4*>(&sW[0][0])[i] = reinterpret_cast<const float4*>(Wd)[i];
    __syncthreads();
    for (int i = t; i < 1024; i += TPB) {
        int r = i >> 5, c4 = i & 31;
        int node = srow[r];
        float4 v = make_float4(0.f, 0.f, 0.f, 0.f);
        if (node >= 0) {
            uint2 u = *reinterpret_cast<const uint2*>(H + (size_t)node * 128 + c4 * 4);
            v = make_float4(bf_lo(u.x), bf_hi(u.x), bf_lo(u.y), bf_hi(u.y));
        }
        reinterpret_cast<float4*>(&sA[r][0])[c4] = v;
    }
    __syncthreads();
    int lane = t & 63, wave = t >> 6;
    int half = lane >> 5;
    int c0 = (lane & 31) * 4;
    int r0 = wave * 8 + half * 4;
    float acc[4][4] = {};
#pragma unroll 8
    for (int k = 0; k < 128; ++k) {
        float4 wv = *reinterpret_cast<const float4*>(&sW[k][c0]);
#pragma unroll
        for (int r = 0; r < 4; ++r) {
            float a = sA[r0 + r][k];
            acc[r][0] += a * wv.x;
            acc[r][1] += a * wv.y;
            acc[r][2] += a * wv.z;
            acc[r][3] += a * wv.w;
        }
    }
    float local = 0.f;
    float4 bv = *reinterpret_cast<const float4*>(bd + c0);
#pragma unroll
    for (int r = 0; r < 4; ++r) {
        int i = bm0 + r0 + r;
        if (i < m) {
            int node = srow[r0 + r];
            float4 at = *reinterpret_cast<const float4*>(attr + (size_t)node * 128 + c0);
            float d0 = acc[r][0] + bv.x - at.x;
            float d1 = acc[r][1] + bv.y - at.y;
            float d2 = acc[r][2] + bv.z - at.z;
            float d3 = acc[r][3] + bv.w - at.w;
            local += d0 * d0 + d1 * d1 + d2 * d2 + d3 * d3;
        }
    }
    red[t] = local;
    __syncthreads();
    for (int off = TPB / 2; off > 0; off >>= 1) {
        if (t < off) red[t] += red[t + off];
        __syncthreads();
    }
    if (t == 0) part[blockIdx.x] = red[0];
}

__global__ void k_final(const float* __restrict__ part, int np, double inv_denom,
                        float* __restrict__ out)
{
    __shared__ double red[TPB];
    int t = threadIdx.x;
    double s = 0.0;
    for (int i = t; i < np; i += TPB) s += (double)part[i];
    red[t] = s;
    __syncthreads();
    for (int off = TPB / 2; off > 0; off >>= 1) {
        if (t < off) red[t] += red[t + off];
        __syncthreads();
    }
    if (t == 0) out[0] = (float)(red[0] * inv_denom);
}

// ---------------- launch ----------------
extern "C" void kernel_launch(void* const* d_in, const int* in_sizes, int n_in,
                              void* d_out, int out_size, void* d_ws, size_t ws_size,
                              hipStream_t stream)
{
    const float* attr = (const float*)d_in[0];
    const int*   src  = (const int*)d_in[1];
    const int*   dst  = (const int*)d_in[2];
    const int*   midx = (const int*)d_in[3];
    const float* W0   = (const float*)d_in[4];
    const float* al0  = (const float*)d_in[5];
    const float* ar0  = (const float*)d_in[6];
    const float* b0   = (const float*)d_in[7];
    const float* W1   = (const float*)d_in[8];
    const float* al1  = (const float*)d_in[9];
    const float* ar1  = (const float*)d_in[10];
    const float* b1   = (const float*)d_in[11];
    const float* Wd   = (const float*)d_in[12];
    const float* bd   = (const float*)d_in[13];
    const float* mtok = (const float*)d_in[14];

    int N = in_sizes[0] / 128;
    int E = in_sizes[1];
    int M = in_sizes[3];

    char* p = (char*)d_ws;
    auto carve = [&](size_t bytes) {
        char* q = p;
        p += (bytes + 255) & ~(size_t)255;
        return q;
    };
    unsigned char*  ff = (unsigned char*)carve((size_t)N * 128);       // fp8 messages (layer 0)
    unsigned short* fb = (unsigned short*)carve((size_t)N * 128 * 2);  // bf16 messages (layer 1)
    unsigned short* hb = (unsigned short*)carve((size_t)N * 128 * 2);  // bf16 layer output
    float* el   = (float*)carve((size_t)N * 4 * 4);
    float* er   = (float*)carve((size_t)N * 4 * 4);
    int*   flag = (int*)carve((size_t)N * 4);
    int*   cnt  = (int*)carve((size_t)N * 32 * 4);   // padded: 1 counter / 128B line
    int*   rp   = (int*)carve((size_t)(N + 1) * 4);
    int*   rank = (int*)carve((size_t)E * 4);
    int*   csrc = (int*)carve((size_t)E * 4);
    unsigned short* bp0 = (unsigned short*)carve(16 * 128 * 8 * 2);
    unsigned short* bp1 = (unsigned short*)carve(16 * 128 * 8 * 2);
    int NB = (N + 2047) / 2048;
    int*   bsum = (int*)carve((size_t)NB * 4);
    int NLB = (M + 31) / 32;
    float* part = (float*)carve((size_t)NLB * 4);
    (void)ws_size; (void)n_in; (void)out_size;

    hipMemsetAsync(flag, 0, (size_t)N * 4, stream);
    hipMemsetAsync(cnt, 0, (size_t)N * 32 * 4, stream);

    k_setflag<<<(M + TPB - 1) / TPB, TPB, 0, stream>>>(midx, flag, M);
    k_count_rank<<<(E + TPB - 1) / TPB, TPB, 0, stream>>>(dst, cnt, rank, E);
    k_scan_block<<<NB, TPB, 0, stream>>>(cnt, rp, bsum, N);
    k_scan_sums<<<1, 64, 0, stream>>>(bsum, rp, NB, N);
    k_scan_add<<<NB, TPB, 0, stream>>>(rp, bsum, N);
    k_fill<<<(E + TPB - 1) / TPB, TPB, 0, stream>>>(dst, src, rank, rp, csrc, E);
    k_packW<<<8, TPB, 0, stream>>>(W0, bp0);
    k_packW<<<8, TPB, 0, stream>>>(W1, bp1);

    int GB = (N + 127) / 128;
    int NAB = (N + 3) / 4;
    int MAB = (M + 3) / 4;
    // layer 0: fp8 messages, full aggregation (all nodes feed layer 1)
    k_gemm_mfma<1, 0, 1><<<GB, TPB, 0, stream>>>(attr, flag, mtok, bp0, al0, ar0, ff, el, er, N);
    k_node_agg8<<<NAB, TPB, 0, stream>>>(ff, el, er, b0, rp, csrc, hb, N);
    // layer 1: bf16 messages, aggregate ONLY mask nodes (decoder reads only those rows)
    k_gemm_mfma<0, 1, 0><<<GB, TPB, 0, stream>>>(hb, nullptr, nullptr, bp1, al1, ar1, fb, el, er, N);
    k_node_agg<1><<<MAB, TPB, 0, stream>>>(fb, el, er, b1, rp, csrc, midx, hb, M);
    // decoder + loss
    k_loss<<<NLB, TPB, 0, stream>>>(hb, midx, Wd, bd, attr, M, part);
    k_final<<<1, TPB, 0, stream>>>(part, NLB, 1.0 / ((double)M * 128.0), (float*)d_out);
}

// Round 14
// 303.738 us; speedup vs baseline: 1.0221x; 1.0221x over previous
//
#include <hip/hip_runtime.h>
#include <cstdint>

#define TPB 256

typedef __attribute__((ext_vector_type(8))) short short8_t;   // 8 bf16
typedef __attribute__((ext_vector_type(4))) float f32x4;
typedef __attribute__((ext_vector_type(2))) float f32x2;

__device__ __forceinline__ float lrelu(float x) { return x > 0.0f ? x : 0.2f * x; }

// round-to-nearest-even fp32 -> bf16
__device__ __forceinline__ unsigned short f2bf(float x) {
    unsigned int u = __float_as_uint(x);
    unsigned int r = (u + 0x7FFFu + ((u >> 16) & 1u)) >> 16;
    return (unsigned short)r;
}
__device__ __forceinline__ float bf_lo(unsigned int u) { return __uint_as_float(u << 16); }
__device__ __forceinline__ float bf_hi(unsigned int u) { return __uint_as_float(u & 0xFFFF0000u); }

// ---------------- fused independent pre-work: count_rank | setflag | packW0 | packW1 ----
// All four are mutually independent; one launch, block-range dispatch.
__global__ void k_build_misc(const int* __restrict__ dst, int* __restrict__ cnt,
                             int* __restrict__ rank, int e, int EB,
                             const int* __restrict__ midx, int* __restrict__ flag, int m, int MB,
                             const float* __restrict__ W0, unsigned short* __restrict__ bp0,
                             const float* __restrict__ W1, unsigned short* __restrict__ bp1)
{
    int b = blockIdx.x;
    if (b < EB) {
        int i = b * TPB + threadIdx.x;
        if (i < e) rank[i] = atomicAdd(&cnt[dst[i] << 5], 1);
    } else if (b < EB + MB) {
        int i = (b - EB) * TPB + threadIdx.x;
        if (i < m) flag[midx[i]] = 1;
    } else {
        int pb = b - EB - MB;
        const float* W = (pb < 8) ? W0 : W1;
        unsigned short* Bp = (pb < 8) ? bp0 : bp1;
        int t = (pb & 7) * TPB + threadIdx.x;
        if (t < 2048) {
            int kb = t >> 7, n = t & 127;
            unsigned int w[4];
#pragma unroll
            for (int j = 0; j < 4; ++j) {
                unsigned int lo = f2bf(W[(kb * 8 + 2 * j) * 128 + n]);
                unsigned int hi = f2bf(W[(kb * 8 + 2 * j + 1) * 128 + n]);
                w[j] = lo | (hi << 16);
            }
            reinterpret_cast<uint4*>(Bp)[t] = make_uint4(w[0], w[1], w[2], w[3]);
        }
    }
}

// exclusive scan over padded cnt (stride 32), dense rp out; 2048 elems/block
__global__ void k_scan_block(const int* __restrict__ cnt, int* __restrict__ rp,
                             int* __restrict__ bsum, int n) {
    __shared__ int ls[TPB];
    int t = threadIdx.x, b = blockIdx.x;
    int base = b * 2048 + t * 8;
    int c[8];
    int tsum = 0;
#pragma unroll
    for (int j = 0; j < 8; ++j) {
        int idx = base + j;
        c[j] = (idx < n) ? cnt[idx << 5] : 0;
        tsum += c[j];
    }
    ls[t] = tsum;
    __syncthreads();
    for (int off = 1; off < TPB; off <<= 1) {
        int v = (t >= off) ? ls[t - off] : 0;
        __syncthreads();
        ls[t] += v;
        __syncthreads();
    }
    int run = ls[t] - tsum;
#pragma unroll
    for (int j = 0; j < 8; ++j) {
        int idx = base + j;
        if (idx < n) rp[idx] = run;
        run += c[j];
    }
    if (t == TPB - 1) bsum[b] = ls[TPB - 1];
}

__global__ void k_scan_sums(int* __restrict__ bsum, int* __restrict__ rp, int nb, int n) {
    int l = threadIdx.x;
    int v = (l < nb) ? bsum[l] : 0;
    int inc = v;
    for (int off = 1; off < 64; off <<= 1) {
        int u = __shfl_up(inc, off);
        if (l >= off) inc += u;
    }
    int tot = __shfl(inc, 63);
    if (l < nb) bsum[l] = inc - v;
    if (l == 0) rp[n] = tot;
}

__global__ void k_scan_add(int* __restrict__ rp, const int* __restrict__ bsum, int n) {
    int b = blockIdx.x;
    int base_v = bsum[b];
    for (int i = threadIdx.x; i < 2048; i += TPB) {
        int idx = b * 2048 + i;
        if (idx < n) rp[idx] += base_v;
    }
}

// ---------------- MFMA bf16 GEMM + fused el/er; LDS-free (device body) ----------------
template <int MASKED, int BF16IN, int FP8OUT>
__device__ __forceinline__ void gemm_body(
    int blk, const void* __restrict__ Ain, const int* __restrict__ flag,
    const float* __restrict__ mtok, const unsigned short* __restrict__ Bpack,
    const float* __restrict__ al, const float* __restrict__ ar,
    void* __restrict__ Fout, float* __restrict__ EL, float* __restrict__ ER, int n)
{
    int t = threadIdx.x;
    int bm0 = blk * 128;
    int w = t >> 6, l = t & 63;
    int lm = l & 15, lg = l >> 4;
    const short8_t* bp = reinterpret_cast<const short8_t*>(Bpack);   // global, L2-hit

    int rowA0 = bm0 + w * 32 + lm;
    int rowA1 = rowA0 + 16;
    int rc0 = rowA0 < n ? rowA0 : n - 1;
    int rc1 = rowA1 < n ? rowA1 : n - 1;

    short8_t af0[4], af1[4];
    if (BF16IN) {
        const unsigned short* A = (const unsigned short*)Ain;
        const unsigned short* pA0 = A + (size_t)rc0 * 128 + lg * 8;
        const unsigned short* pA1 = A + (size_t)rc1 * 128 + lg * 8;
#pragma unroll
        for (int ks = 0; ks < 4; ++ks) {
            af0[ks] = *reinterpret_cast<const short8_t*>(pA0 + ks * 32);
            af1[ks] = *reinterpret_cast<const short8_t*>(pA1 + ks * 32);
        }
    } else {
        const float* A = (const float*)Ain;
        const float* pA0 = A + (size_t)rc0 * 128 + lg * 8;
        const float* pA1 = A + (size_t)rc1 * 128 + lg * 8;
        if (MASKED) {
            if (flag[rc0]) pA0 = mtok + lg * 8;
            if (flag[rc1]) pA1 = mtok + lg * 8;
        }
#pragma unroll
        for (int ks = 0; ks < 4; ++ks) {
            float4 lo0 = *reinterpret_cast<const float4*>(pA0 + ks * 32);
            float4 hi0 = *reinterpret_cast<const float4*>(pA0 + ks * 32 + 4);
            float4 lo1 = *reinterpret_cast<const float4*>(pA1 + ks * 32);
            float4 hi1 = *reinterpret_cast<const float4*>(pA1 + ks * 32 + 4);
            short8_t v0, v1;
            v0[0] = (short)f2bf(lo0.x); v0[1] = (short)f2bf(lo0.y);
            v0[2] = (short)f2bf(lo0.z); v0[3] = (short)f2bf(lo0.w);
            v0[4] = (short)f2bf(hi0.x); v0[5] = (short)f2bf(hi0.y);
            v0[6] = (short)f2bf(hi0.z); v0[7] = (short)f2bf(hi0.w);
            v1[0] = (short)f2bf(lo1.x); v1[1] = (short)f2bf(lo1.y);
            v1[2] = (short)f2bf(lo1.z); v1[3] = (short)f2bf(lo1.w);
            v1[4] = (short)f2bf(hi1.x); v1[5] = (short)f2bf(hi1.y);
            v1[6] = (short)f2bf(hi1.z); v1[7] = (short)f2bf(hi1.w);
            af0[ks] = v0; af1[ks] = v1;
        }
    }

    f32x4 acc[2][8];
#pragma unroll
    for (int mf = 0; mf < 2; ++mf)
#pragma unroll
        for (int f = 0; f < 8; ++f)
            acc[mf][f] = (f32x4){0.f, 0.f, 0.f, 0.f};

#pragma unroll
    for (int ks = 0; ks < 4; ++ks) {
        int kb = ks * 4 + lg;
#pragma unroll
        for (int f = 0; f < 8; ++f) {
            short8_t bfr = bp[kb * 128 + f * 16 + lm];
            acc[0][f] = __builtin_amdgcn_mfma_f32_16x16x32_bf16(af0[ks], bfr, acc[0][f], 0, 0, 0);
            acc[1][f] = __builtin_amdgcn_mfma_f32_16x16x32_bf16(af1[ks], bfr, acc[1][f], 0, 0, 0);
        }
    }

    float alv[8], arv[8];
#pragma unroll
    for (int f = 0; f < 8; ++f) { alv[f] = al[f * 16 + lm]; arv[f] = ar[f * 16 + lm]; }

#pragma unroll
    for (int mf = 0; mf < 2; ++mf) {
#pragma unroll
        for (int r = 0; r < 4; ++r) {
            int row = bm0 + w * 32 + mf * 16 + lg * 4 + r;
            if (row < n) {
                if (FP8OUT) {
                    unsigned char* Ff = (unsigned char*)Fout;
#pragma unroll
                    for (int f = 0; f < 8; ++f) {
                        int pk = __builtin_amdgcn_cvt_pk_fp8_f32(acc[mf][f][r], acc[mf][f][r], 0, false);
                        Ff[(size_t)row * 128 + f * 16 + lm] = (unsigned char)(pk & 0xFF);
                    }
                } else {
                    unsigned short* Fb = (unsigned short*)Fout;
#pragma unroll
                    for (int f = 0; f < 8; ++f)
                        Fb[(size_t)row * 128 + f * 16 + lm] = f2bf(acc[mf][f][r]);
                }
            }
            float pe[4], pr_[4];
#pragma unroll
            for (int h = 0; h < 4; ++h) {
                pe[h]  = acc[mf][2 * h][r] * alv[2 * h] + acc[mf][2 * h + 1][r] * alv[2 * h + 1];
                pr_[h] = acc[mf][2 * h][r] * arv[2 * h] + acc[mf][2 * h + 1][r] * arv[2 * h + 1];
            }
#pragma unroll
            for (int h = 0; h < 4; ++h) {
#pragma unroll
                for (int off = 1; off < 16; off <<= 1) {
                    pe[h]  += __shfl_xor(pe[h], off);
                    pr_[h] += __shfl_xor(pr_[h], off);
                }
            }
            if (lm == 0 && row < n) {
                *reinterpret_cast<float4*>(EL + (size_t)row * 4) = make_float4(pe[0], pe[1], pe[2], pe[3]);
                *reinterpret_cast<float4*>(ER + (size_t)row * 4) = make_float4(pr_[0], pr_[1], pr_[2], pr_[3]);
            }
        }
    }
}

// ---------------- fused: fill (scatter) || gemm0 — independent DAG branches ----------
// fill blocks first (longer workload starts early); gemm blocks after.
__global__ __launch_bounds__(TPB) void k_fill_gemm0(
    const int* __restrict__ dst, const int* __restrict__ src,
    const int* __restrict__ rank, const int* __restrict__ rp,
    int* __restrict__ csrc, int e, int FB,
    const float* __restrict__ A, const int* __restrict__ flag,
    const float* __restrict__ mtok, const unsigned short* __restrict__ bp0,
    const float* __restrict__ al0, const float* __restrict__ ar0,
    unsigned char* __restrict__ ff, float* __restrict__ el, float* __restrict__ er, int n)
{
    int b = blockIdx.x;
    if (b < FB) {
        int i = b * TPB + threadIdx.x;
        if (i < e) csrc[rp[dst[i]] + rank[i]] = src[i];
    } else {
        gemm_body<1, 0, 1>(b - FB, A, flag, mtok, bp0, al0, ar0, ff, el, er, n);
    }
}

// standalone layer-1 GEMM
__global__ __launch_bounds__(TPB) void k_gemm1(
    const unsigned short* __restrict__ A, const unsigned short* __restrict__ bp1,
    const float* __restrict__ al1, const float* __restrict__ ar1,
    unsigned short* __restrict__ fb, float* __restrict__ el, float* __restrict__ er, int n)
{
    gemm_body<0, 1, 0>(blockIdx.x, A, nullptr, nullptr, bp1, al1, ar1, fb, el, er, n);
}

// ---------------- layer-0 agg: fp8 gather, 4 edge-slots, 2-deep pipeline ----------------
__global__ __launch_bounds__(TPB) void k_node_agg8(
    const unsigned char* __restrict__ Ff,
    const float* __restrict__ EL, const float* __restrict__ ER,
    const float* __restrict__ bias,
    const int* __restrict__ rp, const int* __restrict__ csrc,
    unsigned short* __restrict__ OUT, int n)
{
    int l = threadIdx.x & 63;
    int v = blockIdx.x * 4 + (threadIdx.x >> 6);
    if (v >= n) return;
    int p0 = rp[v];
    int deg = rp[v + 1] - p0;
    int j = l >> 4, q = l & 15, h = q >> 2;

    if (deg == 0) {
        if (j == 0) {
            const float* bp = bias + q * 8;
            unsigned int od[4];
#pragma unroll
            for (int k = 0; k < 4; ++k) {
                float o0 = fmaxf(bp[2 * k], 0.f);
                float o1 = fmaxf(bp[2 * k + 1], 0.f);
                od[k] = (unsigned int)f2bf(o0) | ((unsigned int)f2bf(o1) << 16);
            }
            *reinterpret_cast<uint4*>(OUT + (size_t)v * 128 + q * 8) = make_uint4(od[0], od[1], od[2], od[3]);
        }
        return;
    }

    float er_h = ER[(size_t)v * 4 + h];
    f32x2 a[4];
#pragma unroll
    for (int k = 0; k < 4; ++k) a[k] = (f32x2){0.f, 0.f};
    float ssum = 0.f;
    int dm1 = deg - 1;
    int nit = (deg + 3) >> 2;

    int i0 = (j <= dm1) ? j : dm1;
    int e1 = 4 + j; int i1 = (e1 <= dm1) ? e1 : dm1;
    int s0 = csrc[p0 + i0];
    int s1 = csrc[p0 + i1];
    float el0 = EL[(size_t)s0 * 4 + h];
    uint2 u0 = *reinterpret_cast<const uint2*>(Ff + (size_t)s0 * 128 + q * 8);

    for (int it = 0; it < nit; ++it) {
        int e2 = (it + 2) * 4 + j;
        int i2 = (e2 <= dm1) ? e2 : dm1;
        int s2 = csrc[p0 + i2];
        float el1 = EL[(size_t)s1 * 4 + h];
        uint2 u1 = *reinterpret_cast<const uint2*>(Ff + (size_t)s1 * 128 + q * 8);
        float x = __expf(lrelu(el0 + er_h));
        x = (it * 4 + j <= dm1) ? x : 0.f;
        ssum += x;
        f32x2 x2 = {x, x};
        f32x2 c0 = __builtin_amdgcn_cvt_pk_f32_fp8(u0.x, false);
        f32x2 c1 = __builtin_amdgcn_cvt_pk_f32_fp8(u0.x, true);
        f32x2 c2 = __builtin_amdgcn_cvt_pk_f32_fp8(u0.y, false);
        f32x2 c3 = __builtin_amdgcn_cvt_pk_f32_fp8(u0.y, true);
        a[0] += x2 * c0;
        a[1] += x2 * c1;
        a[2] += x2 * c2;
        a[3] += x2 * c3;
        el0 = el1; u0 = u1; s1 = s2;
    }

#pragma unroll
    for (int off = 16; off <= 32; off <<= 1) {
#pragma unroll
        for (int k = 0; k < 4; ++k) {
            a[k].x += __shfl_xor(a[k].x, off);
            a[k].y += __shfl_xor(a[k].y, off);
        }
        ssum += __shfl_xor(ssum, off);
    }
    if (j == 0) {
        float inv = 1.0f / ssum;
        const float* bp = bias + q * 8;
        unsigned int od[4];
#pragma unroll
        for (int k = 0; k < 4; ++k) {
            float o0 = fmaxf(a[k].x * inv + bp[2 * k], 0.f);
            float o1 = fmaxf(a[k].y * inv + bp[2 * k + 1], 0.f);
            od[k] = (unsigned int)f2bf(o0) | ((unsigned int)f2bf(o1) << 16);
        }
        *reinterpret_cast<uint4*>(OUT + (size_t)v * 128 + q * 8) = make_uint4(od[0], od[1], od[2], od[3]);
    }
}

// ---------------- layer-1 agg: bf16 gather, mask-list nodes, 2-deep pipeline ----------------
template <int USE_LIST>
__global__ __launch_bounds__(TPB) void k_node_agg(
    const unsigned short* __restrict__ Fb,
    const float* __restrict__ EL, const float* __restrict__ ER,
    const float* __restrict__ bias,
    const int* __restrict__ rp, const int* __restrict__ csrc,
    const int* __restrict__ vlist,
    unsigned short* __restrict__ OUT, int nwork)
{
    int l = threadIdx.x & 63;
    int widx = blockIdx.x * 4 + (threadIdx.x >> 6);
    if (widx >= nwork) return;
    int v = USE_LIST ? vlist[widx] : widx;
    int p0 = rp[v];
    int deg = rp[v + 1] - p0;
    int j = l >> 4, q = l & 15, h = q >> 2;

    if (deg == 0) {
        if (j == 0) {
            const float* bp = bias + q * 8;
            unsigned int od[4];
#pragma unroll
            for (int k = 0; k < 4; ++k) {
                float o0 = fmaxf(bp[2 * k], 0.f);
                float o1 = fmaxf(bp[2 * k + 1], 0.f);
                od[k] = (unsigned int)f2bf(o0) | ((unsigned int)f2bf(o1) << 16);
            }
            *reinterpret_cast<uint4*>(OUT + (size_t)v * 128 + q * 8) = make_uint4(od[0], od[1], od[2], od[3]);
        }
        return;
    }

    const char* Fc  = (const char*)Fb;
    const char* ELc = (const char*)EL;
    float er_h = ER[(size_t)v * 4 + h];
    unsigned hq_el = (unsigned)h * 4u;
    unsigned q16   = (unsigned)q * 16u;

    f32x2 a0 = {0.f, 0.f}, a1 = {0.f, 0.f}, a2 = {0.f, 0.f}, a3 = {0.f, 0.f};
    float ssum = 0.f;
    int dm1 = deg - 1;
    int nit = (deg + 3) >> 2;

    int i0 = (j <= dm1) ? j : dm1;
    int e1 = 4 + j; int i1 = (e1 <= dm1) ? e1 : dm1;
    int s0 = csrc[p0 + i0];
    int s1 = csrc[p0 + i1];
    float el0 = *(const float*)(ELc + (unsigned)s0 * 16u + hq_el);
    uint4 u0  = *(const uint4*)(Fc + (unsigned)s0 * 256u + q16);

    for (int it = 0; it < nit; ++it) {
        int e2 = (it + 2) * 4 + j;
        int i2 = (e2 <= dm1) ? e2 : dm1;
        int s2 = csrc[p0 + i2];
        float el1 = *(const float*)(ELc + (unsigned)s1 * 16u + hq_el);
        uint4 u1  = *(const uint4*)(Fc + (unsigned)s1 * 256u + q16);
        float x = __expf(lrelu(el0 + er_h));
        x = (it * 4 + j <= dm1) ? x : 0.f;
        ssum += x;
        f32x2 w0; w0.x = bf_lo(u0.x); w0.y = bf_hi(u0.x);
        f32x2 w1; w1.x = bf_lo(u0.y); w1.y = bf_hi(u0.y);
        f32x2 w2; w2.x = bf_lo(u0.z); w2.y = bf_hi(u0.z);
        f32x2 w3; w3.x = bf_lo(u0.w); w3.y = bf_hi(u0.w);
        a0 += x * w0; a1 += x * w1; a2 += x * w2; a3 += x * w3;
        el0 = el1; u0 = u1; s1 = s2;
    }

#pragma unroll
    for (int off = 16; off <= 32; off <<= 1) {
        a0.x += __shfl_xor(a0.x, off); a0.y += __shfl_xor(a0.y, off);
        a1.x += __shfl_xor(a1.x, off); a1.y += __shfl_xor(a1.y, off);
        a2.x += __shfl_xor(a2.x, off); a2.y += __shfl_xor(a2.y, off);
        a3.x += __shfl_xor(a3.x, off); a3.y += __shfl_xor(a3.y, off);
        ssum += __shfl_xor(ssum, off);
    }
    if (j == 0) {
        float inv = 1.0f / ssum;
        const float* bp = bias + q * 8;
        float o[8];
        o[0] = a0.x * inv + bp[0]; o[1] = a0.y * inv + bp[1];
        o[2] = a1.x * inv + bp[2]; o[3] = a1.y * inv + bp[3];
        o[4] = a2.x * inv + bp[4]; o[5] = a2.y * inv + bp[5];
        o[6] = a3.x * inv + bp[6]; o[7] = a3.y * inv + bp[7];
        unsigned int od[4];
#pragma unroll
        for (int k = 0; k < 4; ++k) {
            float o0 = fmaxf(o[2 * k], 0.f);
            float o1 = fmaxf(o[2 * k + 1], 0.f);
            od[k] = (unsigned int)f2bf(o0) | ((unsigned int)f2bf(o1) << 16);
        }
        *reinterpret_cast<uint4*>(OUT + (size_t)v * 128 + q * 8) = make_uint4(od[0], od[1], od[2], od[3]);
    }
}

// ---------------- decoder GEMM on mask rows (bf16 H) + squared-diff partial ----------------
__global__ __launch_bounds__(TPB) void k_loss(
    const unsigned short* __restrict__ H, const int* __restrict__ midx,
    const float* __restrict__ Wd, const float* __restrict__ bd,
    const float* __restrict__ attr, int m, float* __restrict__ part)
{
    __shared__ float sA[32][128];
    __shared__ float sW[128][128];
    __shared__ int srow[32];
    __shared__ float red[TPB];
    int t = threadIdx.x;
    int bm0 = blockIdx.x * 32;
    if (t < 32) {
        int i = bm0 + t;
        srow[t] = (i < m) ? midx[i] : -1;
    }
    for (int i = t; i < 4096; i += TPB)
        reinterpret_cast<float4*>(&sW[0][0])[i] = reinterpret_cast<const float4*>(Wd)[i];
    __syncthreads();
    for (int i = t; i < 1024; i += TPB) {
        int r = i >> 5, c4 = i & 31;
        int node = srow[r];
        float4 v = make_float4(0.f, 0.f, 0.f, 0.f);
        if (node >= 0) {
            uint2 u = *reinterpret_cast<const uint2*>(H + (size_t)node * 128 + c4 * 4);
            v = make_float4(bf_lo(u.x), bf_hi(u.x), bf_lo(u.y), bf_hi(u.y));
        }
        reinterpret_cast<float4*>(&sA[r][0])[c4] = v;
    }
    __syncthreads();
    int lane = t & 63, wave = t >> 6;
    int half = lane >> 5;
    int c0 = (lane & 31) * 4;
    int r0 = wave * 8 + half * 4;
    float acc[4][4] = {};
#pragma unroll 8
    for (int k = 0; k < 128; ++k) {
        float4 wv = *reinterpret_cast<const float4*>(&sW[k][c0]);
#pragma unroll
        for (int r = 0; r < 4; ++r) {
            float a = sA[r0 + r][k];
            acc[r][0] += a * wv.x;
            acc[r][1] += a * wv.y;
            acc[r][2] += a * wv.z;
            acc[r][3] += a * wv.w;
        }
    }
    float local = 0.f;
    float4 bv = *reinterpret_cast<const float4*>(bd + c0);
#pragma unroll
    for (int r = 0; r < 4; ++r) {
        int i = bm0 + r0 + r;
        if (i < m) {
            int node = srow[r0 + r];
            float4 at = *reinterpret_cast<const float4*>(attr + (size_t)node * 128 + c0);
            float d0 = acc[r][0] + bv.x - at.x;
            float d1 = acc[r][1] + bv.y - at.y;
            float d2 = acc[r][2] + bv.z - at.z;
            float d3 = acc[r][3] + bv.w - at.w;
            local += d0 * d0 + d1 * d1 + d2 * d2 + d3 * d3;
        }
    }
    red[t] = local;
    __syncthreads();
    for (int off = TPB / 2; off > 0; off >>= 1) {
        if (t < off) red[t] += red[t + off];
        __syncthreads();
    }
    if (t == 0) part[blockIdx.x] = red[0];
}

__global__ void k_final(const float* __restrict__ part, int np, double inv_denom,
                        float* __restrict__ out)
{
    __shared__ double red[TPB];
    int t = threadIdx.x;
    double s = 0.0;
    for (int i = t; i < np; i += TPB) s += (double)part[i];
    red[t] = s;
    __syncthreads();
    for (int off = TPB / 2; off > 0; off >>= 1) {
        if (t < off) red[t] += red[t + off];
        __syncthreads();
    }
    if (t == 0) out[0] = (float)(red[0] * inv_denom);
}

// ---------------- launch ----------------
extern "C" void kernel_launch(void* const* d_in, const int* in_sizes, int n_in,
                              void* d_out, int out_size, void* d_ws, size_t ws_size,
                              hipStream_t stream)
{
    const float* attr = (const float*)d_in[0];
    const int*   src  = (const int*)d_in[1];
    const int*   dst  = (const int*)d_in[2];
    const int*   midx = (const int*)d_in[3];
    const float* W0   = (const float*)d_in[4];
    const float* al0  = (const float*)d_in[5];
    const float* ar0  = (const float*)d_in[6];
    const float* b0   = (const float*)d_in[7];
    const float* W1   = (const float*)d_in[8];
    const float* al1  = (const float*)d_in[9];
    const float* ar1  = (const float*)d_in[10];
    const float* b1   = (const float*)d_in[11];
    const float* Wd   = (const float*)d_in[12];
    const float* bd   = (const float*)d_in[13];
    const float* mtok = (const float*)d_in[14];

    int N = in_sizes[0] / 128;
    int E = in_sizes[1];
    int M = in_sizes[3];

    char* p = (char*)d_ws;
    auto carve = [&](size_t bytes) {
        char* q = p;
        p += (bytes + 255) & ~(size_t)255;
        return q;
    };
    unsigned char*  ff = (unsigned char*)carve((size_t)N * 128);       // fp8 messages (layer 0)
    unsigned short* fb = (unsigned short*)carve((size_t)N * 128 * 2);  // bf16 messages (layer 1)
    unsigned short* hb = (unsigned short*)carve((size_t)N * 128 * 2);  // bf16 layer output
    float* el   = (float*)carve((size_t)N * 4 * 4);
    float* er   = (float*)carve((size_t)N * 4 * 4);
    int*   flag = (int*)carve((size_t)N * 4);
    int*   cnt  = (int*)carve((size_t)N * 32 * 4);   // padded: 1 counter / 128B line
    int*   rp   = (int*)carve((size_t)(N + 1) * 4);
    int*   rank = (int*)carve((size_t)E * 4);
    int*   csrc = (int*)carve((size_t)E * 4);
    unsigned short* bp0 = (unsigned short*)carve(16 * 128 * 8 * 2);
    unsigned short* bp1 = (unsigned short*)carve(16 * 128 * 8 * 2);
    int NB = (N + 2047) / 2048;
    int*   bsum = (int*)carve((size_t)NB * 4);
    int NLB = (M + 31) / 32;
    float* part = (float*)carve((size_t)NLB * 4);
    (void)ws_size; (void)n_in; (void)out_size;

    hipMemsetAsync(flag, 0, (size_t)N * 4, stream);
    hipMemsetAsync(cnt, 0, (size_t)N * 32 * 4, stream);

    int EB = (E + TPB - 1) / TPB;
    int MB = (M + TPB - 1) / TPB;
    int GB = (N + 127) / 128;
    int NAB = (N + 3) / 4;
    int MAB = (M + 3) / 4;

    // fused independent pre-work: count_rank | setflag | packW0 | packW1
    k_build_misc<<<EB + MB + 16, TPB, 0, stream>>>(dst, cnt, rank, E, EB,
                                                   midx, flag, M, MB,
                                                   W0, bp0, W1, bp1);
    k_scan_block<<<NB, TPB, 0, stream>>>(cnt, rp, bsum, N);
    k_scan_sums<<<1, 64, 0, stream>>>(bsum, rp, NB, N);
    k_scan_add<<<NB, TPB, 0, stream>>>(rp, bsum, N);

    // fused: fill (scatter, FB blocks first) || layer-0 GEMM (independent branches)
    k_fill_gemm0<<<EB + GB, TPB, 0, stream>>>(dst, src, rank, rp, csrc, E, EB,
                                              attr, flag, mtok, bp0, al0, ar0,
                                              ff, el, er, N);
    // layer 0 aggregation (needs ff/el/er + csrc)
    k_node_agg8<<<NAB, TPB, 0, stream>>>(ff, el, er, b0, rp, csrc, hb, N);
    // layer 1
    k_gemm1<<<GB, TPB, 0, stream>>>(hb, bp1, al1, ar1, fb, el, er, N);
    k_node_agg<1><<<MAB, TPB, 0, stream>>>(fb, el, er, b1, rp, csrc, midx, hb, M);
    // decoder + loss
    k_loss<<<NLB, TPB, 0, stream>>>(hb, midx, Wd, bd, attr, M, part);
    k_final<<<1, TPB, 0, stream>>>(part, NLB, 1.0 / ((double)M * 128.0), (float*)d_out);
}

// Round 15
// 290.141 us; speedup vs baseline: 1.0700x; 1.0469x over previous
//
#include <hip/hip_runtime.h>
#include <cstdint>

#define TPB 256

typedef __attribute__((ext_vector_type(8))) short short8_t;   // 8 bf16
typedef __attribute__((ext_vector_type(4))) float f32x4;
typedef __attribute__((ext_vector_type(2))) float f32x2;

__device__ __forceinline__ float lrelu(float x) { return x > 0.0f ? x : 0.2f * x; }

// round-to-nearest-even fp32 -> bf16
__device__ __forceinline__ unsigned short f2bf(float x) {
    unsigned int u = __float_as_uint(x);
    unsigned int r = (u + 0x7FFFu + ((u >> 16) & 1u)) >> 16;
    return (unsigned short)r;
}
__device__ __forceinline__ float bf_lo(unsigned int u) { return __uint_as_float(u << 16); }
__device__ __forceinline__ float bf_hi(unsigned int u) { return __uint_as_float(u & 0xFFFF0000u); }

// ---------------- tiny pre-work: setflag | packW0 | packW1 ----------------
__global__ void k_misc(const int* __restrict__ midx, int* __restrict__ flag, int m, int MB,
                       const float* __restrict__ W0, unsigned short* __restrict__ bp0,
                       const float* __restrict__ W1, unsigned short* __restrict__ bp1)
{
    int b = blockIdx.x;
    if (b < MB) {
        int i = b * TPB + threadIdx.x;
        if (i < m) flag[midx[i]] = 1;
    } else {
        int pb = b - MB;
        const float* W = (pb < 8) ? W0 : W1;
        unsigned short* Bp = (pb < 8) ? bp0 : bp1;
        int t = (pb & 7) * TPB + threadIdx.x;
        if (t < 2048) {
            int kb = t >> 7, n = t & 127;
            unsigned int w[4];
#pragma unroll
            for (int j = 0; j < 4; ++j) {
                unsigned int lo = f2bf(W[(kb * 8 + 2 * j) * 128 + n]);
                unsigned int hi = f2bf(W[(kb * 8 + 2 * j + 1) * 128 + n]);
                w[j] = lo | (hi << 16);
            }
            reinterpret_cast<uint4*>(Bp)[t] = make_uint4(w[0], w[1], w[2], w[3]);
        }
    }
}

// ---------------- MFMA bf16 GEMM + fused el/er; LDS-free (device body) ----------------
template <int MASKED, int BF16IN, int FP8OUT>
__device__ __forceinline__ void gemm_body(
    int blk, const void* __restrict__ Ain, const int* __restrict__ flag,
    const float* __restrict__ mtok, const unsigned short* __restrict__ Bpack,
    const float* __restrict__ al, const float* __restrict__ ar,
    void* __restrict__ Fout, float* __restrict__ EL, float* __restrict__ ER, int n)
{
    int t = threadIdx.x;
    int bm0 = blk * 128;
    int w = t >> 6, l = t & 63;
    int lm = l & 15, lg = l >> 4;
    const short8_t* bp = reinterpret_cast<const short8_t*>(Bpack);   // global, L2-hit

    int rowA0 = bm0 + w * 32 + lm;
    int rowA1 = rowA0 + 16;
    int rc0 = rowA0 < n ? rowA0 : n - 1;
    int rc1 = rowA1 < n ? rowA1 : n - 1;

    short8_t af0[4], af1[4];
    if (BF16IN) {
        const unsigned short* A = (const unsigned short*)Ain;
        const unsigned short* pA0 = A + (size_t)rc0 * 128 + lg * 8;
        const unsigned short* pA1 = A + (size_t)rc1 * 128 + lg * 8;
#pragma unroll
        for (int ks = 0; ks < 4; ++ks) {
            af0[ks] = *reinterpret_cast<const short8_t*>(pA0 + ks * 32);
            af1[ks] = *reinterpret_cast<const short8_t*>(pA1 + ks * 32);
        }
    } else {
        const float* A = (const float*)Ain;
        const float* pA0 = A + (size_t)rc0 * 128 + lg * 8;
        const float* pA1 = A + (size_t)rc1 * 128 + lg * 8;
        if (MASKED) {
            if (flag[rc0]) pA0 = mtok + lg * 8;
            if (flag[rc1]) pA1 = mtok + lg * 8;
        }
#pragma unroll
        for (int ks = 0; ks < 4; ++ks) {
            float4 lo0 = *reinterpret_cast<const float4*>(pA0 + ks * 32);
            float4 hi0 = *reinterpret_cast<const float4*>(pA0 + ks * 32 + 4);
            float4 lo1 = *reinterpret_cast<const float4*>(pA1 + ks * 32);
            float4 hi1 = *reinterpret_cast<const float4*>(pA1 + ks * 32 + 4);
            short8_t v0, v1;
            v0[0] = (short)f2bf(lo0.x); v0[1] = (short)f2bf(lo0.y);
            v0[2] = (short)f2bf(lo0.z); v0[3] = (short)f2bf(lo0.w);
            v0[4] = (short)f2bf(hi0.x); v0[5] = (short)f2bf(hi0.y);
            v0[6] = (short)f2bf(hi0.z); v0[7] = (short)f2bf(hi0.w);
            v1[0] = (short)f2bf(lo1.x); v1[1] = (short)f2bf(lo1.y);
            v1[2] = (short)f2bf(lo1.z); v1[3] = (short)f2bf(lo1.w);
            v1[4] = (short)f2bf(hi1.x); v1[5] = (short)f2bf(hi1.y);
            v1[6] = (short)f2bf(hi1.z); v1[7] = (short)f2bf(hi1.w);
            af0[ks] = v0; af1[ks] = v1;
        }
    }

    f32x4 acc[2][8];
#pragma unroll
    for (int mf = 0; mf < 2; ++mf)
#pragma unroll
        for (int f = 0; f < 8; ++f)
            acc[mf][f] = (f32x4){0.f, 0.f, 0.f, 0.f};

#pragma unroll
    for (int ks = 0; ks < 4; ++ks) {
        int kb = ks * 4 + lg;
#pragma unroll
        for (int f = 0; f < 8; ++f) {
            short8_t bfr = bp[kb * 128 + f * 16 + lm];
            acc[0][f] = __builtin_amdgcn_mfma_f32_16x16x32_bf16(af0[ks], bfr, acc[0][f], 0, 0, 0);
            acc[1][f] = __builtin_amdgcn_mfma_f32_16x16x32_bf16(af1[ks], bfr, acc[1][f], 0, 0, 0);
        }
    }

    float alv[8], arv[8];
#pragma unroll
    for (int f = 0; f < 8; ++f) { alv[f] = al[f * 16 + lm]; arv[f] = ar[f * 16 + lm]; }

#pragma unroll
    for (int mf = 0; mf < 2; ++mf) {
#pragma unroll
        for (int r = 0; r < 4; ++r) {
            int row = bm0 + w * 32 + mf * 16 + lg * 4 + r;
            if (row < n) {
                if (FP8OUT) {
                    unsigned char* Ff = (unsigned char*)Fout;
#pragma unroll
                    for (int f = 0; f < 8; ++f) {
                        int pk = __builtin_amdgcn_cvt_pk_fp8_f32(acc[mf][f][r], acc[mf][f][r], 0, false);
                        Ff[(size_t)row * 128 + f * 16 + lm] = (unsigned char)(pk & 0xFF);
                    }
                } else {
                    unsigned short* Fb = (unsigned short*)Fout;
#pragma unroll
                    for (int f = 0; f < 8; ++f)
                        Fb[(size_t)row * 128 + f * 16 + lm] = f2bf(acc[mf][f][r]);
                }
            }
            float pe[4], pr_[4];
#pragma unroll
            for (int h = 0; h < 4; ++h) {
                pe[h]  = acc[mf][2 * h][r] * alv[2 * h] + acc[mf][2 * h + 1][r] * alv[2 * h + 1];
                pr_[h] = acc[mf][2 * h][r] * arv[2 * h] + acc[mf][2 * h + 1][r] * arv[2 * h + 1];
            }
#pragma unroll
            for (int h = 0; h < 4; ++h) {
#pragma unroll
                for (int off = 1; off < 16; off <<= 1) {
                    pe[h]  += __shfl_xor(pe[h], off);
                    pr_[h] += __shfl_xor(pr_[h], off);
                }
            }
            if (lm == 0 && row < n) {
                *reinterpret_cast<float4*>(EL + (size_t)row * 4) = make_float4(pe[0], pe[1], pe[2], pe[3]);
                *reinterpret_cast<float4*>(ER + (size_t)row * 4) = make_float4(pr_[0], pr_[1], pr_[2], pr_[3]);
            }
        }
    }
}

// ---------------- fused: gemm0 || count_rank — both depend only on k_misc ----------
// gemm blocks first (heavy, start early); count_rank blocks backfill.
__global__ __launch_bounds__(TPB) void k_cr_gemm0(
    const float* __restrict__ A, const int* __restrict__ flag,
    const float* __restrict__ mtok, const unsigned short* __restrict__ bp0,
    const float* __restrict__ al0, const float* __restrict__ ar0,
    unsigned char* __restrict__ ff, float* __restrict__ el, float* __restrict__ er,
    int n, int GB,
    const int* __restrict__ dst, int* __restrict__ cnt, int* __restrict__ rank, int e)
{
    int b = blockIdx.x;
    if (b < GB) {
        gemm_body<1, 0, 1>(b, A, flag, mtok, bp0, al0, ar0, ff, el, er, n);
    } else {
        int i = (b - GB) * TPB + threadIdx.x;
        if (i < e) rank[i] = atomicAdd(&cnt[dst[i] << 5], 1);
    }
}

// exclusive scan over padded cnt (stride 32), dense rp out; 2048 elems/block
__global__ void k_scan_block(const int* __restrict__ cnt, int* __restrict__ rp,
                             int* __restrict__ bsum, int n) {
    __shared__ int ls[TPB];
    int t = threadIdx.x, b = blockIdx.x;
    int base = b * 2048 + t * 8;
    int c[8];
    int tsum = 0;
#pragma unroll
    for (int j = 0; j < 8; ++j) {
        int idx = base + j;
        c[j] = (idx < n) ? cnt[idx << 5] : 0;
        tsum += c[j];
    }
    ls[t] = tsum;
    __syncthreads();
    for (int off = 1; off < TPB; off <<= 1) {
        int v = (t >= off) ? ls[t - off] : 0;
        __syncthreads();
        ls[t] += v;
        __syncthreads();
    }
    int run = ls[t] - tsum;
#pragma unroll
    for (int j = 0; j < 8; ++j) {
        int idx = base + j;
        if (idx < n) rp[idx] = run;
        run += c[j];
    }
    if (t == TPB - 1) bsum[b] = ls[TPB - 1];
}

__global__ void k_scan_sums(int* __restrict__ bsum, int* __restrict__ rp, int nb, int n) {
    int l = threadIdx.x;
    int v = (l < nb) ? bsum[l] : 0;
    int inc = v;
    for (int off = 1; off < 64; off <<= 1) {
        int u = __shfl_up(inc, off);
        if (l >= off) inc += u;
    }
    int tot = __shfl(inc, 63);
    if (l < nb) bsum[l] = inc - v;
    if (l == 0) rp[n] = tot;
}

__global__ void k_scan_add(int* __restrict__ rp, const int* __restrict__ bsum, int n) {
    int b = blockIdx.x;
    int base_v = bsum[b];
    for (int i = threadIdx.x; i < 2048; i += TPB) {
        int idx = b * 2048 + i;
        if (idx < n) rp[idx] += base_v;
    }
}

__global__ void k_fill(const int* __restrict__ dst, const int* __restrict__ src,
                       const int* __restrict__ rank, const int* __restrict__ rp,
                       int* __restrict__ csrc, int e) {
    int i = blockIdx.x * TPB + threadIdx.x;
    if (i < e) csrc[rp[dst[i]] + rank[i]] = src[i];
}

// standalone layer-1 GEMM
__global__ __launch_bounds__(TPB) void k_gemm1(
    const unsigned short* __restrict__ A, const unsigned short* __restrict__ bp1,
    const float* __restrict__ al1, const float* __restrict__ ar1,
    unsigned short* __restrict__ fb, float* __restrict__ el, float* __restrict__ er, int n)
{
    gemm_body<0, 1, 0>(blockIdx.x, A, nullptr, nullptr, bp1, al1, ar1, fb, el, er, n);
}

// ---------------- layer-0 agg: fp8 gather, 8 edge-slots (round-11 form) ----------------
// wave per node; lane: edge-slot j = l>>3 (8 edges/iter), octet q = l&7 (16B, 16 feats)
__global__ __launch_bounds__(TPB) void k_node_agg8(
    const unsigned char* __restrict__ Ff,
    const float* __restrict__ EL, const float* __restrict__ ER,
    const float* __restrict__ bias,
    const int* __restrict__ rp, const int* __restrict__ csrc,
    unsigned short* __restrict__ OUT, int n)
{
    int l = threadIdx.x & 63;
    int v = blockIdx.x * 4 + (threadIdx.x >> 6);
    if (v >= n) return;
    int p0 = rp[v];
    int deg = rp[v + 1] - p0;
    int j = l >> 3, q = l & 7, h = q >> 1;

    if (deg == 0) {
        if (j == 0) {
            const float* bp = bias + q * 16;
            unsigned int od[8];
#pragma unroll
            for (int k = 0; k < 8; ++k) {
                float o0 = fmaxf(bp[2 * k], 0.f);
                float o1 = fmaxf(bp[2 * k + 1], 0.f);
                od[k] = (unsigned int)f2bf(o0) | ((unsigned int)f2bf(o1) << 16);
            }
            uint4* dp = reinterpret_cast<uint4*>(OUT + (size_t)v * 128 + q * 16);
            dp[0] = make_uint4(od[0], od[1], od[2], od[3]);
            dp[1] = make_uint4(od[4], od[5], od[6], od[7]);
        }
        return;
    }

    float er_h = ER[(size_t)v * 4 + h];
    f32x2 a[8];
#pragma unroll
    for (int k = 0; k < 8; ++k) a[k] = (f32x2){0.f, 0.f};
    float ssum = 0.f;
    int dm1 = deg - 1;
    int nit = (deg + 7) >> 3;

    int i0 = (j <= dm1) ? j : dm1;
    int sA = csrc[p0 + i0];
    float elA = EL[(size_t)sA * 4 + h];
    uint4 uA = *reinterpret_cast<const uint4*>(Ff + (size_t)sA * 128 + q * 16);

    for (int it = 0; it < nit; ++it) {
        int eN = (it + 1) * 8 + j;
        int iN = (eN <= dm1) ? eN : dm1;
        int sB = csrc[p0 + iN];                       // prefetch next-iter index
        float x = __expf(lrelu(elA + er_h));
        x = (it * 8 + j <= dm1) ? x : 0.f;
        float elB = EL[(size_t)sB * 4 + h];                                // prefetch
        uint4 uB = *reinterpret_cast<const uint4*>(Ff + (size_t)sB * 128 + q * 16); // prefetch
        ssum += x;
        {
            auto c0 = __builtin_amdgcn_cvt_pk_f32_fp8(uA.x, false);
            auto c1 = __builtin_amdgcn_cvt_pk_f32_fp8(uA.x, true);
            auto c2 = __builtin_amdgcn_cvt_pk_f32_fp8(uA.y, false);
            auto c3 = __builtin_amdgcn_cvt_pk_f32_fp8(uA.y, true);
            auto c4 = __builtin_amdgcn_cvt_pk_f32_fp8(uA.z, false);
            auto c5 = __builtin_amdgcn_cvt_pk_f32_fp8(uA.z, true);
            auto c6 = __builtin_amdgcn_cvt_pk_f32_fp8(uA.w, false);
            auto c7 = __builtin_amdgcn_cvt_pk_f32_fp8(uA.w, true);
            a[0].x += x * c0[0]; a[0].y += x * c0[1];
            a[1].x += x * c1[0]; a[1].y += x * c1[1];
            a[2].x += x * c2[0]; a[2].y += x * c2[1];
            a[3].x += x * c3[0]; a[3].y += x * c3[1];
            a[4].x += x * c4[0]; a[4].y += x * c4[1];
            a[5].x += x * c5[0]; a[5].y += x * c5[1];
            a[6].x += x * c6[0]; a[6].y += x * c6[1];
            a[7].x += x * c7[0]; a[7].y += x * c7[1];
        }
        elA = elB; uA = uB;
    }

#pragma unroll
    for (int off = 8; off <= 32; off <<= 1) {
#pragma unroll
        for (int k = 0; k < 8; ++k) {
            a[k].x += __shfl_xor(a[k].x, off);
            a[k].y += __shfl_xor(a[k].y, off);
        }
        ssum += __shfl_xor(ssum, off);
    }
    if (j == 0) {
        float inv = 1.0f / ssum;
        const float* bp = bias + q * 16;
        unsigned int od[8];
#pragma unroll
        for (int k = 0; k < 8; ++k) {
            float o0 = fmaxf(a[k].x * inv + bp[2 * k], 0.f);
            float o1 = fmaxf(a[k].y * inv + bp[2 * k + 1], 0.f);
            od[k] = (unsigned int)f2bf(o0) | ((unsigned int)f2bf(o1) << 16);
        }
        uint4* dp = reinterpret_cast<uint4*>(OUT + (size_t)v * 128 + q * 16);
        dp[0] = make_uint4(od[0], od[1], od[2], od[3]);
        dp[1] = make_uint4(od[4], od[5], od[6], od[7]);
    }
}

// ---------------- layer-1 agg: bf16 gather, mask-list nodes, 2-deep pipeline ----------------
template <int USE_LIST>
__global__ __launch_bounds__(TPB) void k_node_agg(
    const unsigned short* __restrict__ Fb,
    const float* __restrict__ EL, const float* __restrict__ ER,
    const float* __restrict__ bias,
    const int* __restrict__ rp, const int* __restrict__ csrc,
    const int* __restrict__ vlist,
    unsigned short* __restrict__ OUT, int nwork)
{
    int l = threadIdx.x & 63;
    int widx = blockIdx.x * 4 + (threadIdx.x >> 6);
    if (widx >= nwork) return;
    int v = USE_LIST ? vlist[widx] : widx;
    int p0 = rp[v];
    int deg = rp[v + 1] - p0;
    int j = l >> 4, q = l & 15, h = q >> 2;

    if (deg == 0) {
        if (j == 0) {
            const float* bp = bias + q * 8;
            unsigned int od[4];
#pragma unroll
            for (int k = 0; k < 4; ++k) {
                float o0 = fmaxf(bp[2 * k], 0.f);
                float o1 = fmaxf(bp[2 * k + 1], 0.f);
                od[k] = (unsigned int)f2bf(o0) | ((unsigned int)f2bf(o1) << 16);
            }
            *reinterpret_cast<uint4*>(OUT + (size_t)v * 128 + q * 8) = make_uint4(od[0], od[1], od[2], od[3]);
        }
        return;
    }

    const char* Fc  = (const char*)Fb;
    const char* ELc = (const char*)EL;
    float er_h = ER[(size_t)v * 4 + h];
    unsigned hq_el = (unsigned)h * 4u;
    unsigned q16   = (unsigned)q * 16u;

    f32x2 a0 = {0.f, 0.f}, a1 = {0.f, 0.f}, a2 = {0.f, 0.f}, a3 = {0.f, 0.f};
    float ssum = 0.f;
    int dm1 = deg - 1;
    int nit = (deg + 3) >> 2;

    int i0 = (j <= dm1) ? j : dm1;
    int e1 = 4 + j; int i1 = (e1 <= dm1) ? e1 : dm1;
    int s0 = csrc[p0 + i0];
    int s1 = csrc[p0 + i1];
    float el0 = *(const float*)(ELc + (unsigned)s0 * 16u + hq_el);
    uint4 u0  = *(const uint4*)(Fc + (unsigned)s0 * 256u + q16);

    for (int it = 0; it < nit; ++it) {
        int e2 = (it + 2) * 4 + j;
        int i2 = (e2 <= dm1) ? e2 : dm1;
        int s2 = csrc[p0 + i2];
        float el1 = *(const float*)(ELc + (unsigned)s1 * 16u + hq_el);
        uint4 u1  = *(const uint4*)(Fc + (unsigned)s1 * 256u + q16);
        float x = __expf(lrelu(el0 + er_h));
        x = (it * 4 + j <= dm1) ? x : 0.f;
        ssum += x;
        f32x2 w0; w0.x = bf_lo(u0.x); w0.y = bf_hi(u0.x);
        f32x2 w1; w1.x = bf_lo(u0.y); w1.y = bf_hi(u0.y);
        f32x2 w2; w2.x = bf_lo(u0.z); w2.y = bf_hi(u0.z);
        f32x2 w3; w3.x = bf_lo(u0.w); w3.y = bf_hi(u0.w);
        a0 += x * w0; a1 += x * w1; a2 += x * w2; a3 += x * w3;
        el0 = el1; u0 = u1; s1 = s2;
    }

#pragma unroll
    for (int off = 16; off <= 32; off <<= 1) {
        a0.x += __shfl_xor(a0.x, off); a0.y += __shfl_xor(a0.y, off);
        a1.x += __shfl_xor(a1.x, off); a1.y += __shfl_xor(a1.y, off);
        a2.x += __shfl_xor(a2.x, off); a2.y += __shfl_xor(a2.y, off);
        a3.x += __shfl_xor(a3.x, off); a3.y += __shfl_xor(a3.y, off);
        ssum += __shfl_xor(ssum, off);
    }
    if (j == 0) {
        float inv = 1.0f / ssum;
        const float* bp = bias + q * 8;
        float o[8];
        o[0] = a0.x * inv + bp[0]; o[1] = a0.y * inv + bp[1];
        o[2] = a1.x * inv + bp[2]; o[3] = a1.y * inv + bp[3];
        o[4] = a2.x * inv + bp[4]; o[5] = a2.y * inv + bp[5];
        o[6] = a3.x * inv + bp[6]; o[7] = a3.y * inv + bp[7];
        unsigned int od[4];
#pragma unroll
        for (int k = 0; k < 4; ++k) {
            float o0 = fmaxf(o[2 * k], 0.f);
            float o1 = fmaxf(o[2 * k + 1], 0.f);
            od[k] = (unsigned int)f2bf(o0) | ((unsigned int)f2bf(o1) << 16);
        }
        *reinterpret_cast<uint4*>(OUT + (size_t)v * 128 + q * 8) = make_uint4(od[0], od[1], od[2], od[3]);
    }
}

// ---------------- decoder GEMM on mask rows (bf16 H) + squared-diff partial ----------------
__global__ __launch_bounds__(TPB) void k_loss(
    const unsigned short* __restrict__ H, const int* __restrict__ midx,
    const float* __restrict__ Wd, const float* __restrict__ bd,
    const float* __restrict__ attr, int m, float* __restrict__ part)
{
    __shared__ float sA[32][128];
    __shared__ float sW[128][128];
    __shared__ int srow[32];
    __shared__ float red[TPB];
    int t = threadIdx.x;
    int bm0 = blockIdx.x * 32;
    if (t < 32) {
        int i = bm0 + t;
        srow[t] = (i < m) ? midx[i] : -1;
    }
    for (int i = t; i < 4096; i += TPB)
        reinterpret_cast<float4*>(&sW[0][0])[i] = reinterpret_cast<const float4*>(Wd)[i];
    __syncthreads();
    for (int i = t; i < 1024; i += TPB) {
        int r = i >> 5, c4 = i & 31;
        int node = srow[r];
        float4 v = make_float4(0.f, 0.f, 0.f, 0.f);
        if (node >= 0) {
            uint2 u = *reinterpret_cast<const uint2*>(H + (size_t)node * 128 + c4 * 4);
            v = make_float4(bf_lo(u.x), bf_hi(u.x), bf_lo(u.y), bf_hi(u.y));
        }
        reinterpret_cast<float4*>(&sA[r][0])[c4] = v;
    }
    __syncthreads();
    int lane = t & 63, wave = t >> 6;
    int half = lane >> 5;
    int c0 = (lane & 31) * 4;
    int r0 = wave * 8 + half * 4;
    float acc[4][4] = {};
#pragma unroll 8
    for (int k = 0; k < 128; ++k) {
        float4 wv = *reinterpret_cast<const float4*>(&sW[k][c0]);
#pragma unroll
        for (int r = 0; r < 4; ++r) {
            float a = sA[r0 + r][k];
            acc[r][0] += a * wv.x;
            acc[r][1] += a * wv.y;
            acc[r][2] += a * wv.z;
            acc[r][3] += a * wv.w;
        }
    }
    float local = 0.f;
    float4 bv = *reinterpret_cast<const float4*>(bd + c0);
#pragma unroll
    for (int r = 0; r < 4; ++r) {
        int i = bm0 + r0 + r;
        if (i < m) {
            int node = srow[r0 + r];
            float4 at = *reinterpret_cast<const float4*>(attr + (size_t)node * 128 + c0);
            float d0 = acc[r][0] + bv.x - at.x;
            float d1 = acc[r][1] + bv.y - at.y;
            float d2 = acc[r][2] + bv.z - at.z;
            float d3 = acc[r][3] + bv.w - at.w;
            local += d0 * d0 + d1 * d1 + d2 * d2 + d3 * d3;
        }
    }
    red[t] = local;
    __syncthreads();
    for (int off = TPB / 2; off > 0; off >>= 1) {
        if (t < off) red[t] += red[t + off];
        __syncthreads();
    }
    if (t == 0) part[blockIdx.x] = red[0];
}

__global__ void k_final(const float* __restrict__ part, int np, double inv_denom,
                        float* __restrict__ out)
{
    __shared__ double red[TPB];
    int t = threadIdx.x;
    double s = 0.0;
    for (int i = t; i < np; i += TPB) s += (double)part[i];
    red[t] = s;
    __syncthreads();
    for (int off = TPB / 2; off > 0; off >>= 1) {
        if (t < off) red[t] += red[t + off];
        __syncthreads();
    }
    if (t == 0) out[0] = (float)(red[0] * inv_denom);
}

// ---------------- launch ----------------
extern "C" void kernel_launch(void* const* d_in, const int* in_sizes, int n_in,
                              void* d_out, int out_size, void* d_ws, size_t ws_size,
                              hipStream_t stream)
{
    const float* attr = (const float*)d_in[0];
    const int*   src  = (const int*)d_in[1];
    const int*   dst  = (const int*)d_in[2];
    const int*   midx = (const int*)d_in[3];
    const float* W0   = (const float*)d_in[4];
    const float* al0  = (const float*)d_in[5];
    const float* ar0  = (const float*)d_in[6];
    const float* b0   = (const float*)d_in[7];
    const float* W1   = (const float*)d_in[8];
    const float* al1  = (const float*)d_in[9];
    const float* ar1  = (const float*)d_in[10];
    const float* b1   = (const float*)d_in[11];
    const float* Wd   = (const float*)d_in[12];
    const float* bd   = (const float*)d_in[13];
    const float* mtok = (const float*)d_in[14];

    int N = in_sizes[0] / 128;
    int E = in_sizes[1];
    int M = in_sizes[3];

    char* p = (char*)d_ws;
    auto carve = [&](size_t bytes) {
        char* q = p;
        p += (bytes + 255) & ~(size_t)255;
        return q;
    };
    unsigned char*  ff = (unsigned char*)carve((size_t)N * 128);       // fp8 messages (layer 0)
    unsigned short* fb = (unsigned short*)carve((size_t)N * 128 * 2);  // bf16 messages (layer 1)
    unsigned short* hb = (unsigned short*)carve((size_t)N * 128 * 2);  // bf16 layer output
    float* el   = (float*)carve((size_t)N * 4 * 4);
    float* er   = (float*)carve((size_t)N * 4 * 4);
    int*   flag = (int*)carve((size_t)N * 4);
    int*   cnt  = (int*)carve((size_t)N * 32 * 4);   // padded: 1 counter / 128B line
    int*   rp   = (int*)carve((size_t)(N + 1) * 4);
    int*   rank = (int*)carve((size_t)E * 4);
    int*   csrc = (int*)carve((size_t)E * 4);
    unsigned short* bp0 = (unsigned short*)carve(16 * 128 * 8 * 2);
    unsigned short* bp1 = (unsigned short*)carve(16 * 128 * 8 * 2);
    int NB = (N + 2047) / 2048;
    int*   bsum = (int*)carve((size_t)NB * 4);
    int NLB = (M + 31) / 32;
    float* part = (float*)carve((size_t)NLB * 4);
    (void)ws_size; (void)n_in; (void)out_size;

    hipMemsetAsync(flag, 0, (size_t)N * 4, stream);
    hipMemsetAsync(cnt, 0, (size_t)N * 32 * 4, stream);

    int EB = (E + TPB - 1) / TPB;
    int MB = (M + TPB - 1) / TPB;
    int GB = (N + 127) / 128;
    int NAB = (N + 3) / 4;
    int MAB = (M + 3) / 4;

    // tiny pre-work: setflag | packW0 | packW1 (all needed by k_cr_gemm0)
    k_misc<<<MB + 16, TPB, 0, stream>>>(midx, flag, M, MB, W0, bp0, W1, bp1);
    // fused: layer-0 GEMM (first) || count_rank (backfill) — independent branches
    k_cr_gemm0<<<GB + EB, TPB, 0, stream>>>(attr, flag, mtok, bp0, al0, ar0,
                                            ff, el, er, N, GB,
                                            dst, cnt, rank, E);
    k_scan_block<<<NB, TPB, 0, stream>>>(cnt, rp, bsum, N);
    k_scan_sums<<<1, 64, 0, stream>>>(bsum, rp, NB, N);
    k_scan_add<<<NB, TPB, 0, stream>>>(rp, bsum, N);
    k_fill<<<EB, TPB, 0, stream>>>(dst, src, rank, rp, csrc, E);

    // layer 0 aggregation
    k_node_agg8<<<NAB, TPB, 0, stream>>>(ff, el, er, b0, rp, csrc, hb, N);
    // layer 1
    k_gemm1<<<GB, TPB, 0, stream>>>(hb, bp1, al1, ar1, fb, el, er, N);
    k_node_agg<1><<<MAB, TPB, 0, stream>>>(fb, el, er, b1, rp, csrc, midx, hb, M);
    // decoder + loss
    k_loss<<<NLB, TPB, 0, stream>>>(hb, midx, Wd, bd, attr, M, part);
    k_final<<<1, TPB, 0, stream>>>(part, NLB, 1.0 / ((double)M * 128.0), (float*)d_out);
}